// Round 7
// baseline (211.760 us; speedup 1.0000x reference)
//
#include <hip/hip_runtime.h>

// NNLoss: min over 5x5 shifted neighborhoods of channel-summed L1 distance,
// then global mean. B=16, C=3, H=W=512, fp32.
// R7: software-pipelined blocks. 512 thr, 4 vertical 128x16 tiles per block,
// double-buffered LDS (2 x 3x20x144 floats = 69.1 KB -> 2 blocks/CU).
// Stage t+1 issued into regs before compute t (T14), ds_write into the other
// buffer, ONE barrier per tile. Branch-free boundaries: clamped global
// addresses + per-component PADV select. GW=144 keeps uniform bank spread.

#define PADV (-10000.0f)

constexpr int Bn = 16, Cn = 3, Hn = 512, Wn = 512;
constexpr long PLANE = (long)Hn * Wn;                  // 262144

constexpr int TW = 128, TH = 16;
constexpr int GW = 144;            // LDS col L <-> global col w0-4+L; used L in [2,134)
constexpr int GH = TH + 4;         // 20 rows: h0-2 .. h0+17
constexpr int BLOCK = 512;
constexpr int TPB = 4;             // tiles per block (vertically adjacent)
constexpr int F4ROW = GW / 4;      // 36 float4 per row
constexpr int F4T = Cn * GH * F4ROW;   // 2160 float4 per tile stage
constexpr int SR = 5;              // ceil(2160/512) staging rounds
constexpr int NBLOCKS = Bn * (Wn / TW) * (Hn / TH / TPB);  // 16*4*8 = 512

__global__ __launch_bounds__(BLOCK, 4) void nnloss_main(
    const float* __restrict__ pred, const float* __restrict__ gt,
    float* __restrict__ partial) {
  const int bid = blockIdx.x;
  const int tw = bid & 3;
  const int thg = (bid >> 2) & 7;
  const int b = bid >> 5;
  const int w0 = tw * TW;
  const int h0base = thg * (TH * TPB);

  __shared__ __align__(16) float tile[2][Cn][GH][GW];  // 69,120 B

  const float* gb = gt + (long)b * Cn * PLANE;
  const float* pb = pred + (long)b * Cn * PLANE;

  const int ty = threadIdx.x >> 5;                     // 16 rows
  const int tx = threadIdx.x & 31;                     // 32 strips of 4 px

  // ---- staging: issue loads (clamped, safe) ----
  auto stage_issue = [&](int h0, float4 (&sv)[SR]) {
#pragma unroll
    for (int m = 0; m < SR; ++m) {
      const int idx = threadIdx.x + m * BLOCK;
      if (idx < F4T) {
        const int c = idx / (GH * F4ROW);
        const int rem = idx - c * (GH * F4ROW);
        const int r = rem / F4ROW;
        const int k = rem - r * F4ROW;
        const int gh = h0 - 2 + r;
        const int ghc = min(max(gh, 0), Hn - 1);
        const int col0 = w0 - 4 + 4 * k;
        const int colc = min(max(col0, 0), Wn - 4);
        sv[m] = *(const float4*)(gb + (long)c * PLANE + (long)ghc * Wn + colc);
      }
    }
  };
  // ---- staging: write to LDS buffer nb with PADV for OOB cells ----
  auto stage_write = [&](int h0, const float4 (&sv)[SR], int nb) {
#pragma unroll
    for (int m = 0; m < SR; ++m) {
      const int idx = threadIdx.x + m * BLOCK;
      if (idx < F4T) {
        const int c = idx / (GH * F4ROW);
        const int rem = idx - c * (GH * F4ROW);
        const int r = rem / F4ROW;
        const int k = rem - r * F4ROW;
        const int gh = h0 - 2 + r;
        const int col0 = w0 - 4 + 4 * k;
        const bool rb = (gh < 0) || (gh >= Hn);
        float4 v = sv[m];
        v.x = (rb || (col0 + 0) < 0 || (col0 + 0) >= Wn) ? PADV : v.x;
        v.y = (rb || (col0 + 1) < 0 || (col0 + 1) >= Wn) ? PADV : v.y;
        v.z = (rb || (col0 + 2) < 0 || (col0 + 2) >= Wn) ? PADV : v.z;
        v.w = (rb || (col0 + 3) < 0 || (col0 + 3) >= Wn) ? PADV : v.w;
        *(float4*)&tile[nb][c][r][4 * k] = v;
      }
    }
  };
  // ---- pred load: 4 consecutive px per thread ----
  auto pred_load = [&](int h0, float (&p)[Cn][4]) {
    const float* pp = pb + (long)(h0 + ty) * Wn + (w0 + 4 * tx);
#pragma unroll
    for (int c = 0; c < Cn; ++c) {
      const float4 v = *(const float4*)(pp + (long)c * PLANE);
      p[c][0] = v.x; p[c][1] = v.y; p[c][2] = v.z; p[c][3] = v.w;
    }
  };
  // ---- compute one tile from LDS buffer cb ----
  auto compute = [&](const float (&p)[Cn][4], int cb) -> float {
    float mm[4] = {3.0e38f, 3.0e38f, 3.0e38f, 3.0e38f};
#pragma unroll
    for (int di = 0; di < 5; ++di) {
      const int lr = ty + di;
      float s[5][4];
#pragma unroll
      for (int c = 0; c < Cn; ++c) {
        const float* base = &tile[cb][c][lr][4 * tx];
        const float4 A = *(const float4*)(base);
        const float4 Bq = *(const float4*)(base + 4);
        const float2 Cq = *(const float2*)(base + 8);
        float g[10];
        g[0] = A.x;  g[1] = A.y;  g[2] = A.z;  g[3] = A.w;
        g[4] = Bq.x; g[5] = Bq.y; g[6] = Bq.z; g[7] = Bq.w;
        g[8] = Cq.x; g[9] = Cq.y;
        if (c == 0) {
#pragma unroll
          for (int dj = 0; dj < 5; ++dj)
#pragma unroll
            for (int q = 0; q < 4; ++q)
              s[dj][q] = fabsf(g[q + dj + 2] - p[0][q]);
        } else {
#pragma unroll
          for (int dj = 0; dj < 5; ++dj)
#pragma unroll
            for (int q = 0; q < 4; ++q)
              s[dj][q] += fabsf(g[q + dj + 2] - p[c][q]);
        }
      }
#pragma unroll
      for (int q = 0; q < 4; ++q) {
        const float t1 = fminf(fminf(s[0][q], s[1][q]), s[2][q]);  // v_min3
        const float t2 = fminf(fminf(t1, s[3][q]), s[4][q]);       // v_min3
        mm[q] = fminf(mm[q], t2);
      }
    }
    return (mm[0] + mm[1]) + (mm[2] + mm[3]);
  };

  // ---- pipelined tile loop ----
  float4 sv[SR];
  float pcur[Cn][4], pnext[Cn][4];

  stage_issue(h0base, sv);
  pred_load(h0base, pcur);
  stage_write(h0base, sv, 0);
  __syncthreads();

  float vacc = 0.f;
#pragma unroll
  for (int t = 0; t < TPB; ++t) {
    const int h0 = h0base + t * TH;
    if (t < TPB - 1) {
      stage_issue(h0 + TH, sv);        // in flight across compute
      pred_load(h0 + TH, pnext);
    }
    vacc += compute(pcur, t & 1);
    if (t < TPB - 1) {
      stage_write(h0 + TH, sv, (t + 1) & 1);   // other buffer: no race
#pragma unroll
      for (int c = 0; c < Cn; ++c)
#pragma unroll
        for (int q = 0; q < 4; ++q) pcur[c][q] = pnext[c][q];
    }
    __syncthreads();
  }

  // ---- block reduction ----
#pragma unroll
  for (int off = 32; off > 0; off >>= 1) vacc += __shfl_down(vacc, off, 64);
  __shared__ float wsum[BLOCK / 64];
  const int lane = threadIdx.x & 63;
  const int wid = threadIdx.x >> 6;
  if (lane == 0) wsum[wid] = vacc;
  __syncthreads();
  if (threadIdx.x == 0) {
    float tsum = 0.f;
#pragma unroll
    for (int i = 0; i < BLOCK / 64; ++i) tsum += wsum[i];
    partial[bid] = tsum;
  }
}

__global__ __launch_bounds__(256) void nnloss_reduce(
    const float* __restrict__ partial, float* __restrict__ out) {
  double acc = 0.0;
  for (int i = threadIdx.x; i < NBLOCKS; i += 256) acc += (double)partial[i];
#pragma unroll
  for (int off = 32; off > 0; off >>= 1) acc += __shfl_down(acc, off, 64);
  __shared__ double sd[4];
  const int lane = threadIdx.x & 63;
  const int wid = threadIdx.x >> 6;
  if (lane == 0) sd[wid] = acc;
  __syncthreads();
  if (threadIdx.x == 0) {
    const double tot = (sd[0] + sd[1]) + (sd[2] + sd[3]);
    out[0] = (float)(tot / ((double)Bn * Hn * Wn));
  }
}

extern "C" void kernel_launch(void* const* d_in, const int* in_sizes, int n_in,
                              void* d_out, int out_size, void* d_ws, size_t ws_size,
                              hipStream_t stream) {
  const float* pred = (const float*)d_in[0];
  const float* gt = (const float*)d_in[1];
  // d_in[2], d_in[3] are nh=5, nw=5 (hard-coded)
  float* out = (float*)d_out;
  float* partial = (float*)d_ws;  // 512 floats

  nnloss_main<<<NBLOCKS, BLOCK, 0, stream>>>(pred, gt, partial);
  nnloss_reduce<<<1, 256, 0, stream>>>(partial, out);
}

// Round 8
// 158.264 us; speedup vs baseline: 1.3380x; 1.3380x over previous
//
#include <hip/hip_runtime.h>

// NNLoss: min over 5x5 shifted neighborhoods of channel-summed L1 distance,
// then global mean. B=16, C=3, H=W=512, fp32.
// R8: no LDS at all. Each thread owns a 4 px x 4 row patch held in registers;
// gt rows stream through VGPRs via direct global loads (L1/L2-served).
// Zero barriers, zero ds ops. Row-boundary guard only for row-groups 0 and
// 127 (wave-uniform template split); column edges patched with cndmask.

#define PADV (-10000.0f)

constexpr int Bn = 16, Cn = 3, Hn = 512, Wn = 512;
constexpr long PLANE = (long)Hn * Wn;                  // 262144

constexpr int BLOCK = 256;
constexpr int SW = Wn / 4;                             // 128 strips per row
constexpr int RG = Hn / 4;                             // 128 row-groups
constexpr int NTHREADS = Bn * RG * SW;                 // 262144
constexpr int NBLOCKS = NTHREADS / BLOCK;              // 1024

template <bool GUARD>
__device__ __forceinline__ float strip_work(const float* __restrict__ gb,
                                            const float* __restrict__ pb,
                                            int h0, int w0, bool lo, bool hi) {
  // predicted: 4 rows x 3 ch x 4 px (always in-bounds)
  float p[4][Cn][4];
#pragma unroll
  for (int hh = 0; hh < 4; ++hh)
#pragma unroll
    for (int c = 0; c < Cn; ++c) {
      const float4 v =
          *(const float4*)(pb + (long)c * PLANE + (long)(h0 + hh) * Wn + w0);
      p[hh][c][0] = v.x; p[hh][c][1] = v.y; p[hh][c][2] = v.z; p[hh][c][3] = v.w;
    }

  float m[4][4];
#pragma unroll
  for (int hh = 0; hh < 4; ++hh)
#pragma unroll
    for (int q = 0; q < 4; ++q) m[hh][q] = 3.0e38f;

  // window cols for pixels w0..w0+3 are w0-2 .. w0+5 ; g[k] = col w0-2+k
  const int cLo = max(w0 - 2, 0);                      // f2 (8B-aligned)
  const int cHi = min(w0 + 4, Wn - 2);                 // f2 (8B-aligned)

#pragma unroll
  for (int rr = 0; rr < 8; ++rr) {                     // gt rows h0-2 .. h0+5
    const int gr = h0 - 2 + rr;
    const int grc = GUARD ? min(max(gr, 0), Hn - 1) : gr;
    const bool rok = GUARD ? (gr >= 0 && gr < Hn) : true;

    float g[Cn][8];
#pragma unroll
    for (int c = 0; c < Cn; ++c) {
      const float* row = gb + (long)c * PLANE + (long)grc * Wn;
      const float2 l2 = *(const float2*)(row + cLo);
      const float4 md = *(const float4*)(row + w0);
      const float2 h2 = *(const float2*)(row + cHi);
      g[c][0] = lo ? PADV : l2.x;
      g[c][1] = lo ? PADV : l2.y;
      g[c][2] = md.x; g[c][3] = md.y; g[c][4] = md.z; g[c][5] = md.w;
      g[c][6] = hi ? PADV : h2.x;
      g[c][7] = hi ? PADV : h2.y;
      if (GUARD) {
#pragma unroll
        for (int k = 0; k < 8; ++k) g[c][k] = rok ? g[c][k] : PADV;
      }
    }

    // gt row rr serves output row hh with di = rr - hh in [0,4]
#pragma unroll
    for (int hh = 0; hh < 4; ++hh) {
      const int di = rr - hh;
      if (di < 0 || di > 4) continue;                  // compile-time pruned
      float s[5][4];
#pragma unroll
      for (int dj = 0; dj < 5; ++dj)
#pragma unroll
        for (int q = 0; q < 4; ++q)
          s[dj][q] = fabsf(g[0][q + dj] - p[hh][0][q]);
#pragma unroll
      for (int c = 1; c < Cn; ++c)
#pragma unroll
        for (int dj = 0; dj < 5; ++dj)
#pragma unroll
          for (int q = 0; q < 4; ++q)
            s[dj][q] += fabsf(g[c][q + dj] - p[hh][c][q]);
#pragma unroll
      for (int q = 0; q < 4; ++q) {
        const float t1 = fminf(fminf(s[0][q], s[1][q]), s[2][q]);  // v_min3
        const float t2 = fminf(fminf(t1, s[3][q]), s[4][q]);       // v_min3
        m[hh][q] = fminf(m[hh][q], t2);
      }
    }
  }

  float v = 0.f;
#pragma unroll
  for (int hh = 0; hh < 4; ++hh)
    v += (m[hh][0] + m[hh][1]) + (m[hh][2] + m[hh][3]);
  return v;
}

__global__ __launch_bounds__(BLOCK, 4) void nnloss_main(
    const float* __restrict__ pred, const float* __restrict__ gt,
    float* __restrict__ partial) {
  const int gid = blockIdx.x * BLOCK + threadIdx.x;
  const int tx = gid & (SW - 1);
  const int rg = (gid >> 7) & (RG - 1);
  const int b = gid >> 14;
  const int w0 = 4 * tx;
  const int h0 = 4 * rg;

  const float* gb = gt + (long)b * Cn * PLANE;
  const float* pb = pred + (long)b * Cn * PLANE;
  const bool lo = (tx == 0);
  const bool hi = (tx == SW - 1);

  float v;
  if (rg >= 1 && rg <= RG - 2)                         // wave-uniform branch
    v = strip_work<false>(gb, pb, h0, w0, lo, hi);
  else
    v = strip_work<true>(gb, pb, h0, w0, lo, hi);

  // ---- wave + block reduction ----
#pragma unroll
  for (int off = 32; off > 0; off >>= 1) v += __shfl_down(v, off, 64);
  __shared__ float wsum[BLOCK / 64];
  const int lane = threadIdx.x & 63;
  const int wid = threadIdx.x >> 6;
  if (lane == 0) wsum[wid] = v;
  __syncthreads();
  if (threadIdx.x == 0)
    partial[blockIdx.x] = (wsum[0] + wsum[1]) + (wsum[2] + wsum[3]);
}

__global__ __launch_bounds__(256) void nnloss_reduce(
    const float* __restrict__ partial, float* __restrict__ out) {
  double acc = 0.0;
  for (int i = threadIdx.x; i < NBLOCKS; i += 256) acc += (double)partial[i];
#pragma unroll
  for (int off = 32; off > 0; off >>= 1) acc += __shfl_down(acc, off, 64);
  __shared__ double sd[4];
  const int lane = threadIdx.x & 63;
  const int wid = threadIdx.x >> 6;
  if (lane == 0) sd[wid] = acc;
  __syncthreads();
  if (threadIdx.x == 0) {
    const double tot = (sd[0] + sd[1]) + (sd[2] + sd[3]);
    out[0] = (float)(tot / ((double)Bn * Hn * Wn));
  }
}

extern "C" void kernel_launch(void* const* d_in, const int* in_sizes, int n_in,
                              void* d_out, int out_size, void* d_ws, size_t ws_size,
                              hipStream_t stream) {
  const float* pred = (const float*)d_in[0];
  const float* gt = (const float*)d_in[1];
  // d_in[2], d_in[3] are nh=5, nw=5 (hard-coded)
  float* out = (float*)d_out;
  float* partial = (float*)d_ws;  // 1024 floats = 4 KB

  nnloss_main<<<NBLOCKS, BLOCK, 0, stream>>>(pred, gt, partial);
  nnloss_reduce<<<1, 256, 0, stream>>>(partial, out);
}

// Round 9
// 40.071 us; speedup vs baseline: 5.2846x; 3.9496x over previous
//
#include <hip/hip_runtime.h>

// NNLoss: min over 5x5 shifted neighborhoods of channel-summed L1 distance,
// then global mean. B=16, C=3, H=W=512, fp32.
// R9: R8's no-LDS register-blocked design (4 px x 4 rows per thread, gt rows
// streamed through VGPRs, zero barriers / LDS), with the VGPR cap fixed:
// __launch_bounds__(256,2) -> cap 128 (empirical rule: cap = 256/arg; arg=4
// capped at 64 and spilled R7/R8 into scratch).

#define PADV (-10000.0f)

constexpr int Bn = 16, Cn = 3, Hn = 512, Wn = 512;
constexpr long PLANE = (long)Hn * Wn;                  // 262144

constexpr int BLOCK = 256;
constexpr int SW = Wn / 4;                             // 128 strips per row
constexpr int RG = Hn / 4;                             // 128 row-groups
constexpr int NTHREADS = Bn * RG * SW;                 // 262144
constexpr int NBLOCKS = NTHREADS / BLOCK;              // 1024

template <bool GUARD>
__device__ __forceinline__ float strip_work(const float* __restrict__ gb,
                                            const float* __restrict__ pb,
                                            int h0, int w0, bool lo, bool hi) {
  // predicted: 4 rows x 3 ch x 4 px (always in-bounds)
  float p[4][Cn][4];
#pragma unroll
  for (int hh = 0; hh < 4; ++hh)
#pragma unroll
    for (int c = 0; c < Cn; ++c) {
      const float4 v =
          *(const float4*)(pb + (long)c * PLANE + (long)(h0 + hh) * Wn + w0);
      p[hh][c][0] = v.x; p[hh][c][1] = v.y; p[hh][c][2] = v.z; p[hh][c][3] = v.w;
    }

  float m[4][4];
#pragma unroll
  for (int hh = 0; hh < 4; ++hh)
#pragma unroll
    for (int q = 0; q < 4; ++q) m[hh][q] = 3.0e38f;

  // window cols for pixels w0..w0+3 are w0-2 .. w0+5 ; g[k] = col w0-2+k
  const int cLo = max(w0 - 2, 0);                      // f2 (8B-aligned)
  const int cHi = min(w0 + 4, Wn - 2);                 // f2 (8B-aligned)

#pragma unroll
  for (int rr = 0; rr < 8; ++rr) {                     // gt rows h0-2 .. h0+5
    const int gr = h0 - 2 + rr;
    const int grc = GUARD ? min(max(gr, 0), Hn - 1) : gr;
    const bool rok = GUARD ? (gr >= 0 && gr < Hn) : true;

    float g[Cn][8];
#pragma unroll
    for (int c = 0; c < Cn; ++c) {
      const float* row = gb + (long)c * PLANE + (long)grc * Wn;
      const float2 l2 = *(const float2*)(row + cLo);
      const float4 md = *(const float4*)(row + w0);
      const float2 h2 = *(const float2*)(row + cHi);
      g[c][0] = lo ? PADV : l2.x;
      g[c][1] = lo ? PADV : l2.y;
      g[c][2] = md.x; g[c][3] = md.y; g[c][4] = md.z; g[c][5] = md.w;
      g[c][6] = hi ? PADV : h2.x;
      g[c][7] = hi ? PADV : h2.y;
      if (GUARD) {
#pragma unroll
        for (int k = 0; k < 8; ++k) g[c][k] = rok ? g[c][k] : PADV;
      }
    }

    // gt row rr serves output row hh with di = rr - hh in [0,4]
#pragma unroll
    for (int hh = 0; hh < 4; ++hh) {
      const int di = rr - hh;
      if (di < 0 || di > 4) continue;                  // compile-time pruned
      float s[5][4];
#pragma unroll
      for (int dj = 0; dj < 5; ++dj)
#pragma unroll
        for (int q = 0; q < 4; ++q)
          s[dj][q] = fabsf(g[0][q + dj] - p[hh][0][q]);
#pragma unroll
      for (int c = 1; c < Cn; ++c)
#pragma unroll
        for (int dj = 0; dj < 5; ++dj)
#pragma unroll
          for (int q = 0; q < 4; ++q)
            s[dj][q] += fabsf(g[c][q + dj] - p[hh][c][q]);
#pragma unroll
      for (int q = 0; q < 4; ++q) {
        const float t1 = fminf(fminf(s[0][q], s[1][q]), s[2][q]);  // v_min3
        const float t2 = fminf(fminf(t1, s[3][q]), s[4][q]);       // v_min3
        m[hh][q] = fminf(m[hh][q], t2);
      }
    }
  }

  float v = 0.f;
#pragma unroll
  for (int hh = 0; hh < 4; ++hh)
    v += (m[hh][0] + m[hh][1]) + (m[hh][2] + m[hh][3]);
  return v;
}

__global__ __launch_bounds__(BLOCK, 2) void nnloss_main(
    const float* __restrict__ pred, const float* __restrict__ gt,
    float* __restrict__ partial) {
  const int gid = blockIdx.x * BLOCK + threadIdx.x;
  const int tx = gid & (SW - 1);
  const int rg = (gid >> 7) & (RG - 1);
  const int b = gid >> 14;
  const int w0 = 4 * tx;
  const int h0 = 4 * rg;

  const float* gb = gt + (long)b * Cn * PLANE;
  const float* pb = pred + (long)b * Cn * PLANE;
  const bool lo = (tx == 0);
  const bool hi = (tx == SW - 1);

  float v;
  if (rg >= 1 && rg <= RG - 2)                         // wave-uniform branch
    v = strip_work<false>(gb, pb, h0, w0, lo, hi);
  else
    v = strip_work<true>(gb, pb, h0, w0, lo, hi);

  // ---- wave + block reduction ----
#pragma unroll
  for (int off = 32; off > 0; off >>= 1) v += __shfl_down(v, off, 64);
  __shared__ float wsum[BLOCK / 64];
  const int lane = threadIdx.x & 63;
  const int wid = threadIdx.x >> 6;
  if (lane == 0) wsum[wid] = v;
  __syncthreads();
  if (threadIdx.x == 0)
    partial[blockIdx.x] = (wsum[0] + wsum[1]) + (wsum[2] + wsum[3]);
}

__global__ __launch_bounds__(256) void nnloss_reduce(
    const float* __restrict__ partial, float* __restrict__ out) {
  double acc = 0.0;
  for (int i = threadIdx.x; i < NBLOCKS; i += 256) acc += (double)partial[i];
#pragma unroll
  for (int off = 32; off > 0; off >>= 1) acc += __shfl_down(acc, off, 64);
  __shared__ double sd[4];
  const int lane = threadIdx.x & 63;
  const int wid = threadIdx.x >> 6;
  if (lane == 0) sd[wid] = acc;
  __syncthreads();
  if (threadIdx.x == 0) {
    const double tot = (sd[0] + sd[1]) + (sd[2] + sd[3]);
    out[0] = (float)(tot / ((double)Bn * Hn * Wn));
  }
}

extern "C" void kernel_launch(void* const* d_in, const int* in_sizes, int n_in,
                              void* d_out, int out_size, void* d_ws, size_t ws_size,
                              hipStream_t stream) {
  const float* pred = (const float*)d_in[0];
  const float* gt = (const float*)d_in[1];
  // d_in[2], d_in[3] are nh=5, nw=5 (hard-coded)
  float* out = (float*)d_out;
  float* partial = (float*)d_ws;  // 1024 floats = 4 KB

  nnloss_main<<<NBLOCKS, BLOCK, 0, stream>>>(pred, gt, partial);
  nnloss_reduce<<<1, 256, 0, stream>>>(partial, out);
}